// Round 5
// baseline (207.057 us; speedup 1.0000x reference)
//
#include <hip/hip_runtime.h>
#include <hip/hip_bf16.h>

// Sizes fixed by the problem
#define B2      2
#define NX      20000
#define F_IN    128
#define NS1     16000
#define ND1     8000
#define E1      100000
#define ND2     4000
#define E2      60000
#define HEADS   12
#define CH      128
#define K1      1536   // HEADS*CH
#define MROWS   (2*ND1) // 16000

typedef __bf16 bf16x8 __attribute__((ext_vector_type(8)));
typedef float  f32x4  __attribute__((ext_vector_type(4)));

static __device__ __forceinline__ float lrelu(float x) { return x > 0.f ? x : 0.2f * x; }

static __device__ __forceinline__ unsigned short f2bf(float f) {
    union { float f; unsigned u; } v; v.f = f;
    unsigned r = v.u + 0x7fffu + ((v.u >> 16) & 1u);
    return (unsigned short)(r >> 16);
}
static __device__ __forceinline__ float bf2f(unsigned short h) {
    union { unsigned u; float f; } v; v.u = ((unsigned)h) << 16;
    return v.f;
}

// ---------------------------------------------------------------------------
// Fused prep: blocks [0,4000) convA, [4000,4768) convB, [4768,4784) ws.
// convA: xg[32000][128] bf16 = gather(x via n_id1).
// convB: W1T[1536][128] bf16 = transpose(W1).
// ws:    wswd[32][128]  bf16: n<12 -> W1_h@a_src[h]; 12..23 -> a_dst; else 0.
// ---------------------------------------------------------------------------
__global__ __launch_bounds__(256) void k_prep(const float* __restrict__ x,
                                              const int* __restrict__ n_id,
                                              const float* __restrict__ W,
                                              const float* __restrict__ asrc,
                                              const float* __restrict__ adst,
                                              unsigned short* __restrict__ xg,
                                              unsigned short* __restrict__ WT,
                                              unsigned short* __restrict__ wswd)
{
    const int bx = blockIdx.x;
    const int tid = threadIdx.x;
    if (bx < 4000) {
        int t = bx * 256 + tid;                      // float4 units
        int row = t >> 5;
        int c4 = (t & 31) << 2;
        int b = row >= NS1 ? 1 : 0;
        int node = n_id[row - b * NS1];
        const float4 v = *reinterpret_cast<const float4*>(
            x + ((size_t)(b * NX + node)) * F_IN + c4);
        ushort4 o;
        o.x = f2bf(v.x); o.y = f2bf(v.y); o.z = f2bf(v.z); o.w = f2bf(v.w);
        *reinterpret_cast<ushort4*>(xg + (size_t)row * F_IN + c4) = o;
    } else if (bx < 4768) {
        int t = (bx - 4000) * 256 + tid;             // 0..196607
        int k = t / K1;
        int n = t - k * K1;
        WT[(size_t)n * F_IN + k] = f2bf(W[t]);
    } else {
        int t = (bx - 4768) * 256 + tid;             // 0..4095
        int n = t >> 7;
        int c = t & 127;
        float acc = 0.f;
        if (n < 24) {
            int h = n < 12 ? n : n - 12;
            const float* att = (n < 12 ? asrc : adst) + h * CH;
            const float* wr = W + (size_t)c * K1 + h * CH;
            for (int j = 0; j < CH; ++j) acc += wr[j] * att[j];
        }
        wswd[(size_t)n * F_IN + c] = f2bf(acc);
    }
}

// ---------------------------------------------------------------------------
// Scores: [32000,128] @ wswd^T -> es[row][12], ed[row][12].  MFMA.
// ---------------------------------------------------------------------------
__global__ __launch_bounds__(256) void k_escore(const unsigned short* __restrict__ xg,
                                                const unsigned short* __restrict__ wswd,
                                                float* __restrict__ es,
                                                float* __restrict__ ed)
{
    const int tid = threadIdx.x;
    const int wave = tid >> 6, lane = tid & 63;
    const int l15 = lane & 15, l4 = lane >> 4;
    const int rt = blockIdx.x * 4 + wave;            // 0..1999
    const int row0 = rt * 16;
    const unsigned short* Ap = xg + (size_t)(row0 + l15) * F_IN + l4 * 8;

    f32x4 acc[2] = {f32x4{0,0,0,0}, f32x4{0,0,0,0}};
#pragma unroll
    for (int kk = 0; kk < 4; ++kk) {
        bf16x8 a = *reinterpret_cast<const bf16x8*>(Ap + kk * 32);
#pragma unroll
        for (int c = 0; c < 2; ++c) {
            bf16x8 b = *reinterpret_cast<const bf16x8*>(
                wswd + (size_t)(c * 16 + l15) * F_IN + kk * 32 + l4 * 8);
            acc[c] = __builtin_amdgcn_mfma_f32_16x16x32_bf16(a, b, acc[c], 0, 0, 0);
        }
    }
#pragma unroll
    for (int c = 0; c < 2; ++c) {
        int col = c * 16 + l15;
#pragma unroll
        for (int r = 0; r < 4; ++r) {
            int row = row0 + l4 * 4 + r;
            float v = acc[c][r];
            if (col < 12)       es[(size_t)row * HEADS + col] = v;
            else if (col < 24)  ed[(size_t)row * HEADS + (col - 12)] = v;
        }
    }
}

// ---------------------------------------------------------------------------
// CSR build (both graphs fused): count -> scan (2 blocks) -> scatter.
// deg/cur: [0,ND1) graph1, [ND1,ND1+ND2) graph2.  eid: [0,E1) g1, [E1,..) g2.
// ---------------------------------------------------------------------------
__global__ void k_count2(const int* __restrict__ dst1, const int* __restrict__ dst2,
                         int* __restrict__ deg)
{
    int e = blockIdx.x * 256 + threadIdx.x;
    if (e < E1) atomicAdd(&deg[dst1[e]], 1);
    else if (e < E1 + E2) atomicAdd(&deg[ND1 + dst2[e - E1]], 1);
}

static __device__ void scan_body(const int* __restrict__ deg, int n,
                                 int* __restrict__ off, int* __restrict__ cursor)
{
    __shared__ int wsum[16];
    __shared__ int carry_sh;
    int tid = threadIdx.x, lane = tid & 63, wid = tid >> 6;
    if (tid == 0) { carry_sh = 0; off[0] = 0; }
    __syncthreads();
    for (int base = 0; base < n; base += 1024) {
        int i = base + tid;
        int v = (i < n) ? deg[i] : 0;
        int s = v;
#pragma unroll
        for (int o = 1; o < 64; o <<= 1) {
            int t = __shfl_up(s, o);
            if (lane >= o) s += t;
        }
        if (lane == 63) wsum[wid] = s;
        __syncthreads();
        if (wid == 0) {
            int t = (lane < 16) ? wsum[lane] : 0;
#pragma unroll
            for (int o = 1; o < 16; o <<= 1) {
                int u = __shfl_up(t, o);
                if (lane >= o) t += u;
            }
            if (lane < 16) wsum[lane] = t;
        }
        __syncthreads();
        int carry = carry_sh;
        int wexcl = (wid == 0) ? 0 : wsum[wid - 1];
        int incl = carry + wexcl + s;
        if (i < n) { off[i + 1] = incl; cursor[i] = incl - v; }
        __syncthreads();
        if (tid == 0) carry_sh = carry + wsum[15];
        __syncthreads();
    }
}

__global__ __launch_bounds__(1024) void k_scan2(const int* __restrict__ deg,
                                                int* __restrict__ off1,
                                                int* __restrict__ off2,
                                                int* __restrict__ cur)
{
    if (blockIdx.x == 0) scan_body(deg, ND1, off1, cur);
    else                 scan_body(deg + ND1, ND2, off2, cur + ND1);
}

__global__ void k_scatter2(const int* __restrict__ dst1, const int* __restrict__ dst2,
                           int* __restrict__ cur, int* __restrict__ eid)
{
    int e = blockIdx.x * 256 + threadIdx.x;
    if (e < E1) {
        int p = atomicAdd(&cur[dst1[e]], 1);
        eid[p] = e;
    } else if (e < E1 + E2) {
        int p = atomicAdd(&cur[ND1 + dst2[e - E1]], 1);
        eid[E1 + p] = e - E1;
    }
}

// ---------------------------------------------------------------------------
// Layer-1 aggregate in F=128 space: ONE WAVE per (dst i, batch b).
// Wave-synchronous: no LDS, no barriers. Lane owns channels {2l,2l+1} x 12 h.
// Phase A (per 64-edge chunk): lane e computes its edge's 12 scores + exp;
// cross-lane max merge. Phase B: per edge, readlane-broadcast w + coalesced
// xg row load + 24 FMA.
// ---------------------------------------------------------------------------
__global__ __launch_bounds__(256) void k_agg1(const unsigned short* __restrict__ xg,
                                              const float* __restrict__ es,
                                              const float* __restrict__ ed,
                                              const int* __restrict__ res1,
                                              const int* __restrict__ off,
                                              const int* __restrict__ eid,
                                              const int* __restrict__ src1,
                                              unsigned short* __restrict__ agg)
{
    const int tid = threadIdx.x;
    const int w = tid >> 6, lane = tid & 63;
    const int i = blockIdx.x * 4 + w;   // dst node
    const int b = blockIdx.y;           // batch

    const int beg = off[i], end = off[i + 1];
    const int deg = end - beg;

    // per-head dst-score (uniform across wave)
    const float* edp = ed + ((size_t)(b * NS1 + res1[i])) * HEADS;
    float edv[12];
    {
        float4 t0 = *reinterpret_cast<const float4*>(edp);
        float4 t1 = *reinterpret_cast<const float4*>(edp + 4);
        float4 t2 = *reinterpret_cast<const float4*>(edp + 8);
        edv[0]=t0.x; edv[1]=t0.y; edv[2]=t0.z; edv[3]=t0.w;
        edv[4]=t1.x; edv[5]=t1.y; edv[6]=t1.z; edv[7]=t1.w;
        edv[8]=t2.x; edv[9]=t2.y; edv[10]=t2.z; edv[11]=t2.w;
    }

    float m[12], den[12], acc[24];
#pragma unroll
    for (int h = 0; h < 12; ++h) { m[h] = -1e30f; den[h] = 0.f; }
#pragma unroll
    for (int r = 0; r < 24; ++r) acc[r] = 0.f;

    for (int cbeg = 0; cbeg < deg; cbeg += 64) {
        const int cnt = min(64, deg - cbeg);
        float al[12];
        int srcr = 0;
        if (lane < cnt) {
            int e = eid[beg + cbeg + lane];
            srcr = src1[e];
            const float4* esp = reinterpret_cast<const float4*>(
                es + ((size_t)(b * NS1 + srcr)) * HEADS);
            float4 u0 = esp[0], u1 = esp[1], u2 = esp[2];
            float ev[12] = {u0.x,u0.y,u0.z,u0.w, u1.x,u1.y,u1.z,u1.w,
                            u2.x,u2.y,u2.z,u2.w};
#pragma unroll
            for (int h = 0; h < 12; ++h) al[h] = lrelu(ev[h] + edv[h]);
        } else {
#pragma unroll
            for (int h = 0; h < 12; ++h) al[h] = -1e30f;
        }

        // chunk max per head (uniform result), merge, rescale, per-lane exp
        float wv[12];
#pragma unroll
        for (int h = 0; h < 12; ++h) {
            float cm = al[h];
#pragma unroll
            for (int o = 32; o > 0; o >>= 1) cm = fmaxf(cm, __shfl_xor(cm, o));
            float nm = fmaxf(m[h], cm);
            float fac = __expf(m[h] - nm);          // 0 on first chunk (underflow)
            den[h] *= fac;
            acc[2*h]   *= fac;
            acc[2*h+1] *= fac;
            m[h] = nm;
            float e = __expf(al[h] - nm);           // lane>=cnt: exp(-1e30-nm)=0
            wv[h] = e;
            den[h] += e;                             // lane-local partial
        }

        // accumulate: per edge broadcast w + coalesced row load
        for (int e = 0; e < cnt; ++e) {
            int se = __shfl(srcr, e);
            unsigned xv = *reinterpret_cast<const unsigned*>(
                xg + ((size_t)(b * NS1 + se)) * F_IN + 2 * lane);
            float x0 = bf2f((unsigned short)(xv & 0xffff));
            float x1 = bf2f((unsigned short)(xv >> 16));
#pragma unroll
            for (int h = 0; h < 12; ++h) {
                float wh = __shfl(wv[h], e);
                acc[2*h]   += wh * x0;
                acc[2*h+1] += wh * x1;
            }
        }
    }

    // finalize: cross-lane den reduce, divide, pack, write
    const size_t rowbase = ((size_t)(b * ND1 + i)) * K1;
#pragma unroll
    for (int h = 0; h < 12; ++h) {
        float d = den[h];
#pragma unroll
        for (int o = 32; o > 0; o >>= 1) d += __shfl_xor(d, o);
        float r = 1.f / (d + 1e-16f);
        unsigned short o0 = f2bf(acc[2*h]   * r);
        unsigned short o1 = f2bf(acc[2*h+1] * r);
        unsigned pack = (unsigned)o0 | ((unsigned)o1 << 16);
        *reinterpret_cast<unsigned*>(agg + rowbase + h * CH + 2 * lane) = pack;
    }
}

// ---------------------------------------------------------------------------
// Post-aggregation projection, head-split for occupancy:
// block (bx, h): 64 rows x 1 head -> s2p[h*MROWS+row]; k_red12 sums heads.
// ---------------------------------------------------------------------------
__global__ __launch_bounds__(256) void k_out1(const unsigned short* __restrict__ agg,
                                              const unsigned short* __restrict__ WT,
                                              const float* __restrict__ bias1,
                                              const float* __restrict__ W2,
                                              float* __restrict__ s2p)
{
    const int tid = threadIdx.x;
    const int wave = tid >> 6, lane = tid & 63;
    const int l15 = lane & 15, l4 = lane >> 4;
    const int row0 = blockIdx.x * 64 + wave * 16;
    const int h = blockIdx.y;

    f32x4 acc[8];
#pragma unroll
    for (int c = 0; c < 8; ++c) acc[c] = f32x4{0, 0, 0, 0};
    const unsigned short* Ap = agg + (size_t)(row0 + l15) * K1 + h * CH + l4 * 8;
#pragma unroll
    for (int kk = 0; kk < 4; ++kk) {
        bf16x8 a = *reinterpret_cast<const bf16x8*>(Ap + kk * 32);
#pragma unroll
        for (int c = 0; c < 8; ++c) {
            bf16x8 bb = *reinterpret_cast<const bf16x8*>(
                WT + (size_t)(h * CH + c * 16 + l15) * F_IN + kk * 32 + l4 * 8);
            acc[c] = __builtin_amdgcn_mfma_f32_16x16x32_bf16(a, bb, acc[c], 0, 0, 0);
        }
    }
    float partial[4] = {0.f, 0.f, 0.f, 0.f};
#pragma unroll
    for (int c = 0; c < 8; ++c) {
        int n = h * CH + c * 16 + l15;
        float bi = bias1[n];
        float w2 = W2[n];
#pragma unroll
        for (int r = 0; r < 4; ++r) {
            float v = acc[c][r] + bi;
            v = v > 0.f ? v : 0.f;
            partial[r] += v * w2;
        }
    }
#pragma unroll
    for (int r = 0; r < 4; ++r) {
#pragma unroll
        for (int o = 1; o < 16; o <<= 1) partial[r] += __shfl_xor(partial[r], o);
    }
    if (l15 == 0) {
#pragma unroll
        for (int r = 0; r < 4; ++r)
            s2p[(size_t)h * MROWS + row0 + l4 * 4 + r] = partial[r];
    }
}

__global__ __launch_bounds__(256) void k_red12(const float* __restrict__ s2p,
                                               float* __restrict__ s2)
{
    int t = blockIdx.x * 256 + threadIdx.x;
    if (t >= MROWS) return;
    float s = 0.f;
#pragma unroll
    for (int h = 0; h < HEADS; ++h) s += s2p[(size_t)h * MROWS + t];
    s2[t] = s;
}

// ---------------------------------------------------------------------------
// Layer-2 (heads=1, ch=1): one thread per (dst j, batch b).
// ---------------------------------------------------------------------------
__global__ void k_agg2(const float* __restrict__ s2,
                       const int* __restrict__ off,
                       const int* __restrict__ eid,
                       const int* __restrict__ src2,
                       const int* __restrict__ res2,
                       const float* __restrict__ asrc,
                       const float* __restrict__ adst,
                       const float* __restrict__ bias2,
                       float* __restrict__ out)
{
    int t = blockIdx.x * 256 + threadIdx.x;
    if (t >= 2 * ND2) return;
    int b = t / ND2, j = t - b * ND2;
    float a_s = asrc[0], a_d = adst[0];
    float edl = s2[(size_t)b * ND1 + res2[j]] * a_d;
    int beg = off[j], end = off[j + 1];
    float m = -INFINITY;
    for (int p = beg; p < end; ++p) {
        int s = src2[eid[p]];
        m = fmaxf(m, lrelu(s2[b * ND1 + s] * a_s + edl));
    }
    float den = 0.f, num = 0.f;
    for (int p = beg; p < end; ++p) {
        int s = src2[eid[p]];
        float v = s2[b * ND1 + s];
        float al = lrelu(v * a_s + edl);
        float w = __expf(al - m);
        den += w;
        num += w * v;
    }
    float o = (end > beg) ? num / (den + 1e-16f) : 0.f;
    out[(size_t)b * ND2 + j] = o + bias2[0];
}

// ---------------------------------------------------------------------------
extern "C" void kernel_launch(void* const* d_in, const int* in_sizes, int n_in,
                              void* d_out, int out_size, void* d_ws, size_t ws_size,
                              hipStream_t stream)
{
    const float* x        = (const float*)d_in[0];
    const int* n_id1      = (const int*)d_in[1];
    const int* res_n_id1  = (const int*)d_in[2];
    const int* src1       = (const int*)d_in[3];
    const int* dst1       = (const int*)d_in[4];
    const int* res_n_id2  = (const int*)d_in[5];
    const int* src2       = (const int*)d_in[6];
    const int* dst2       = (const int*)d_in[7];
    const float* W1       = (const float*)d_in[8];
    const float* att_src1 = (const float*)d_in[9];
    const float* att_dst1 = (const float*)d_in[10];
    const float* bias1    = (const float*)d_in[11];
    const float* W2       = (const float*)d_in[12];
    const float* att_src2 = (const float*)d_in[13];
    const float* att_dst2 = (const float*)d_in[14];
    const float* bias2    = (const float*)d_in[15];

    // workspace layout (16B aligned)
    unsigned short* xg   = (unsigned short*)d_ws;            // 4,096,000
    unsigned short* W1T  = xg + (size_t)2 * NS1 * F_IN;      //   196,608
    unsigned short* wswd = W1T + (size_t)K1 * F_IN;          //     4,096
    unsigned short* agg  = wswd + (size_t)32 * F_IN;         // 24,576,000
    float* es  = (float*)(agg + (size_t)2 * ND1 * K1);       //   384,000
    float* ed  = es + (size_t)2 * NS1 * HEADS;               //   384,000
    float* s2  = ed + (size_t)2 * NS1 * HEADS;               //    16,000
    int* deg   = (int*)(s2 + (size_t)2 * ND1);               // 12,000 (g1|g2)
    int* off1  = deg + (ND1 + ND2);                          // 8001
    int* off2  = off1 + (ND1 + 1);                           // 4001
    int* cur   = off2 + (ND2 + 1);                           // 12,000
    int* eid   = cur + (ND1 + ND2);                          // 160,000 (g1|g2)
    float* s2p = (float*)(eid + E1 + E2);                    // 192,000 f32

    hipMemsetAsync(deg, 0, (ND1 + ND2) * sizeof(int), stream);

    // fused prep (convA + convB + ws)
    k_prep<<<4784, 256, 0, stream>>>(x, n_id1, W1, att_src1, att_dst1,
                                     xg, W1T, wswd);

    // scores for all 32000 rows
    k_escore<<<500, 256, 0, stream>>>(xg, wswd, es, ed);

    // CSR (both graphs)
    k_count2<<<(E1 + E2 + 255) / 256, 256, 0, stream>>>(dst1, dst2, deg);
    k_scan2<<<2, 1024, 0, stream>>>(deg, off1, off2, cur);
    k_scatter2<<<(E1 + E2 + 255) / 256, 256, 0, stream>>>(dst1, dst2, cur, eid);

    // layer-1 softmax-aggregate in F space (wave per dst)
    k_agg1<<<dim3(ND1 / 4, B2), 256, 0, stream>>>(xg, es, ed, res_n_id1,
                                                  off1, eid, src1, agg);

    // projection + bias + relu + dot(W2) -> s2p (per head), then reduce
    k_out1<<<dim3(MROWS / 64, HEADS), 256, 0, stream>>>(agg, W1T, bias1, W2, s2p);
    k_red12<<<(MROWS + 255) / 256, 256, 0, stream>>>(s2p, s2);

    // layer-2
    k_agg2<<<(2 * ND2 + 255) / 256, 256, 0, stream>>>(s2, off2, eid + E1, src2,
                                                      res_n_id2, att_src2,
                                                      att_dst2, bias2,
                                                      (float*)d_out);
}

// Round 6
// 164.355 us; speedup vs baseline: 1.2598x; 1.2598x over previous
//
#include <hip/hip_runtime.h>
#include <hip/hip_bf16.h>

// Sizes fixed by the problem
#define B2      2
#define NX      20000
#define F_IN    128
#define NS1     16000
#define ND1     8000
#define E1      100000
#define ND2     4000
#define E2      60000
#define HEADS   12
#define CH      128
#define K1      1536   // HEADS*CH
#define MROWS   (2*ND1) // 16000

typedef __bf16 bf16x8 __attribute__((ext_vector_type(8)));
typedef float  f32x4  __attribute__((ext_vector_type(4)));

static __device__ __forceinline__ float lrelu(float x) { return x > 0.f ? x : 0.2f * x; }

static __device__ __forceinline__ unsigned short f2bf(float f) {
    union { float f; unsigned u; } v; v.f = f;
    unsigned r = v.u + 0x7fffu + ((v.u >> 16) & 1u);
    return (unsigned short)(r >> 16);
}
static __device__ __forceinline__ float bf2f(unsigned short h) {
    union { unsigned u; float f; } v; v.u = ((unsigned)h) << 16;
    return v.f;
}

// ---------------------------------------------------------------------------
// Fused prep: [0,4000) convA | [4000,4768) convB | [4768,4784) ws | rest: deg=0
// ---------------------------------------------------------------------------
__global__ __launch_bounds__(256) void k_prep(const float* __restrict__ x,
                                              const int* __restrict__ n_id,
                                              const float* __restrict__ W,
                                              const float* __restrict__ asrc,
                                              const float* __restrict__ adst,
                                              unsigned short* __restrict__ xg,
                                              unsigned short* __restrict__ WT,
                                              unsigned short* __restrict__ wswd,
                                              int* __restrict__ deg)
{
    const int bx = blockIdx.x;
    const int tid = threadIdx.x;
    if (bx < 4000) {
        int t = bx * 256 + tid;                      // float4 units
        int row = t >> 5;
        int c4 = (t & 31) << 2;
        int b = row >= NS1 ? 1 : 0;
        int node = n_id[row - b * NS1];
        const float4 v = *reinterpret_cast<const float4*>(
            x + ((size_t)(b * NX + node)) * F_IN + c4);
        ushort4 o;
        o.x = f2bf(v.x); o.y = f2bf(v.y); o.z = f2bf(v.z); o.w = f2bf(v.w);
        *reinterpret_cast<ushort4*>(xg + (size_t)row * F_IN + c4) = o;
    } else if (bx < 4768) {
        int t = (bx - 4000) * 256 + tid;             // 0..196607
        int k = t / K1;
        int n = t - k * K1;
        WT[(size_t)n * F_IN + k] = f2bf(W[t]);
    } else if (bx < 4784) {
        int t = (bx - 4768) * 256 + tid;             // 0..4095
        int n = t >> 7;
        int c = t & 127;
        float acc = 0.f;
        if (n < 24) {
            int h = n < 12 ? n : n - 12;
            const float* att = (n < 12 ? asrc : adst) + h * CH;
            const float* wr = W + (size_t)c * K1 + h * CH;
            for (int j = 0; j < CH; ++j) acc += wr[j] * att[j];
        }
        wswd[(size_t)n * F_IN + c] = f2bf(acc);
    } else {
        int t = (bx - 4784) * 256 + tid;
        if (t < ND1 + ND2) deg[t] = 0;
    }
}

// ---------------------------------------------------------------------------
// Fused: [0,500) scores MFMA | [500,1125) edge-count for both graphs.
// ---------------------------------------------------------------------------
__global__ __launch_bounds__(256) void k_escore_count(
        const unsigned short* __restrict__ xg,
        const unsigned short* __restrict__ wswd,
        const int* __restrict__ dst1, const int* __restrict__ dst2,
        float* __restrict__ es, float* __restrict__ ed,
        int* __restrict__ deg)
{
    const int tid = threadIdx.x;
    if (blockIdx.x < 500) {
        const int wave = tid >> 6, lane = tid & 63;
        const int l15 = lane & 15, l4 = lane >> 4;
        const int rt = blockIdx.x * 4 + wave;            // 0..1999
        const int row0 = rt * 16;
        const unsigned short* Ap = xg + (size_t)(row0 + l15) * F_IN + l4 * 8;

        f32x4 acc[2] = {f32x4{0,0,0,0}, f32x4{0,0,0,0}};
#pragma unroll
        for (int kk = 0; kk < 4; ++kk) {
            bf16x8 a = *reinterpret_cast<const bf16x8*>(Ap + kk * 32);
#pragma unroll
            for (int c = 0; c < 2; ++c) {
                bf16x8 b = *reinterpret_cast<const bf16x8*>(
                    wswd + (size_t)(c * 16 + l15) * F_IN + kk * 32 + l4 * 8);
                acc[c] = __builtin_amdgcn_mfma_f32_16x16x32_bf16(a, b, acc[c], 0, 0, 0);
            }
        }
#pragma unroll
        for (int c = 0; c < 2; ++c) {
            int col = c * 16 + l15;
#pragma unroll
            for (int r = 0; r < 4; ++r) {
                int row = row0 + l4 * 4 + r;
                float v = acc[c][r];
                if (col < 12)       es[(size_t)row * HEADS + col] = v;
                else if (col < 24)  ed[(size_t)row * HEADS + (col - 12)] = v;
            }
        }
    } else {
        int e = (blockIdx.x - 500) * 256 + tid;
        if (e < E1) atomicAdd(&deg[dst1[e]], 1);
        else if (e < E1 + E2) atomicAdd(&deg[ND1 + dst2[e - E1]], 1);
    }
}

// ---------------------------------------------------------------------------
// CSR scan (2 blocks: one per graph) -> scatter
// ---------------------------------------------------------------------------
static __device__ void scan_body(const int* __restrict__ deg, int n,
                                 int* __restrict__ off, int* __restrict__ cursor)
{
    __shared__ int wsum[16];
    __shared__ int carry_sh;
    int tid = threadIdx.x, lane = tid & 63, wid = tid >> 6;
    if (tid == 0) { carry_sh = 0; off[0] = 0; }
    __syncthreads();
    for (int base = 0; base < n; base += 1024) {
        int i = base + tid;
        int v = (i < n) ? deg[i] : 0;
        int s = v;
#pragma unroll
        for (int o = 1; o < 64; o <<= 1) {
            int t = __shfl_up(s, o);
            if (lane >= o) s += t;
        }
        if (lane == 63) wsum[wid] = s;
        __syncthreads();
        if (wid == 0) {
            int t = (lane < 16) ? wsum[lane] : 0;
#pragma unroll
            for (int o = 1; o < 16; o <<= 1) {
                int u = __shfl_up(t, o);
                if (lane >= o) t += u;
            }
            if (lane < 16) wsum[lane] = t;
        }
        __syncthreads();
        int carry = carry_sh;
        int wexcl = (wid == 0) ? 0 : wsum[wid - 1];
        int incl = carry + wexcl + s;
        if (i < n) { off[i + 1] = incl; cursor[i] = incl - v; }
        __syncthreads();
        if (tid == 0) carry_sh = carry + wsum[15];
        __syncthreads();
    }
}

__global__ __launch_bounds__(1024) void k_scan2(const int* __restrict__ deg,
                                                int* __restrict__ off1,
                                                int* __restrict__ off2,
                                                int* __restrict__ cur)
{
    if (blockIdx.x == 0) scan_body(deg, ND1, off1, cur);
    else                 scan_body(deg + ND1, ND2, off2, cur + ND1);
}

__global__ void k_scatter2(const int* __restrict__ dst1, const int* __restrict__ dst2,
                           int* __restrict__ cur, int* __restrict__ eid)
{
    int e = blockIdx.x * 256 + threadIdx.x;
    if (e < E1) {
        int p = atomicAdd(&cur[dst1[e]], 1);
        eid[p] = e;
    } else if (e < E1 + E2) {
        int p = atomicAdd(&cur[ND1 + dst2[e - E1]], 1);
        eid[E1 + p] = e - E1;
    }
}

// ---------------------------------------------------------------------------
// Layer-1 aggregate in F space, NO max-subtraction (shift-invariant softmax;
// scores are O(+-7) << 88, f32-exp safe). Block per (dst,b), 256 threads:
// thread = (channel-pair c2 = (tid&63)*2, head-group hg = tid>>6 of 3 heads).
// Per edge: 1 coalesced dword xg load + 3 LDS broadcasts + 6 FMA + 3 den adds.
// ---------------------------------------------------------------------------
#define CHUNK 64
__global__ __launch_bounds__(256) void k_agg1(const unsigned short* __restrict__ xg,
                                              const float* __restrict__ es,
                                              const float* __restrict__ ed,
                                              const int* __restrict__ res1,
                                              const int* __restrict__ off,
                                              const int* __restrict__ eid,
                                              const int* __restrict__ src1,
                                              unsigned short* __restrict__ agg)
{
    const int i = blockIdx.x;   // dst node
    const int b = blockIdx.y;   // batch
    const int tid = threadIdx.x;
    const int c2 = (tid & 63) * 2;
    const int hg = tid >> 6;            // heads 3hg..3hg+2

    __shared__ float a_ch[CHUNK][HEADS];   // exp(lrelu(score)) per (edge, head)
    __shared__ int   src_sh[CHUNK];
    __shared__ float ed_sh[HEADS];

    const int beg = off[i], end = off[i + 1];
    const int deg = end - beg;

    if (tid < HEADS)
        ed_sh[tid] = ed[((size_t)(b * NS1 + res1[i])) * HEADS + tid];

    float acc[6] = {0.f, 0.f, 0.f, 0.f, 0.f, 0.f};
    float den[3] = {0.f, 0.f, 0.f};
    __syncthreads();

    for (int cbeg = 0; cbeg < deg; cbeg += CHUNK) {
        const int cnt = min(CHUNK, deg - cbeg);
        if (tid < cnt) src_sh[tid] = src1[eid[beg + cbeg + tid]];
        __syncthreads();
        for (int idx = tid; idx < cnt * HEADS; idx += 256) {
            int e = idx / HEADS, h = idx - e * HEADS;
            float al = es[((size_t)(b * NS1 + src_sh[e])) * HEADS + h] + ed_sh[h];
            a_ch[e][h] = __expf(lrelu(al));
        }
        __syncthreads();
#pragma unroll 2
        for (int e = 0; e < cnt; ++e) {
            int se = src_sh[e];
            unsigned xv = *reinterpret_cast<const unsigned*>(
                xg + ((size_t)(b * NS1 + se)) * F_IN + c2);
            float x0 = bf2f((unsigned short)(xv & 0xffff));
            float x1 = bf2f((unsigned short)(xv >> 16));
            float w0 = a_ch[e][3 * hg + 0];
            float w1 = a_ch[e][3 * hg + 1];
            float w2 = a_ch[e][3 * hg + 2];
            acc[0] += w0 * x0; acc[1] += w0 * x1;
            acc[2] += w1 * x0; acc[3] += w1 * x1;
            acc[4] += w2 * x0; acc[5] += w2 * x1;
            den[0] += w0; den[1] += w1; den[2] += w2;
        }
        __syncthreads();
    }

    const size_t rowbase = ((size_t)(b * ND1 + i)) * K1;
#pragma unroll
    for (int j = 0; j < 3; ++j) {
        float r = 1.f / (den[j] + 1e-16f);
        unsigned short o0 = f2bf(acc[2 * j] * r);
        unsigned short o1 = f2bf(acc[2 * j + 1] * r);
        unsigned pack = (unsigned)o0 | ((unsigned)o1 << 16);
        *reinterpret_cast<unsigned*>(agg + rowbase + (3 * hg + j) * CH + c2) = pack;
    }
}

// ---------------------------------------------------------------------------
// Post-aggregation projection, head-split: block (bx, h) = 64 rows x 1 head.
// ---------------------------------------------------------------------------
__global__ __launch_bounds__(256) void k_out1(const unsigned short* __restrict__ agg,
                                              const unsigned short* __restrict__ WT,
                                              const float* __restrict__ bias1,
                                              const float* __restrict__ W2,
                                              float* __restrict__ s2p)
{
    const int tid = threadIdx.x;
    const int wave = tid >> 6, lane = tid & 63;
    const int l15 = lane & 15, l4 = lane >> 4;
    const int row0 = blockIdx.x * 64 + wave * 16;
    const int h = blockIdx.y;

    f32x4 acc[8];
#pragma unroll
    for (int c = 0; c < 8; ++c) acc[c] = f32x4{0, 0, 0, 0};
    const unsigned short* Ap = agg + (size_t)(row0 + l15) * K1 + h * CH + l4 * 8;
#pragma unroll
    for (int kk = 0; kk < 4; ++kk) {
        bf16x8 a = *reinterpret_cast<const bf16x8*>(Ap + kk * 32);
#pragma unroll
        for (int c = 0; c < 8; ++c) {
            bf16x8 bb = *reinterpret_cast<const bf16x8*>(
                WT + (size_t)(h * CH + c * 16 + l15) * F_IN + kk * 32 + l4 * 8);
            acc[c] = __builtin_amdgcn_mfma_f32_16x16x32_bf16(a, bb, acc[c], 0, 0, 0);
        }
    }
    float partial[4] = {0.f, 0.f, 0.f, 0.f};
#pragma unroll
    for (int c = 0; c < 8; ++c) {
        int n = h * CH + c * 16 + l15;
        float bi = bias1[n];
        float w2 = W2[n];
#pragma unroll
        for (int r = 0; r < 4; ++r) {
            float v = acc[c][r] + bi;
            v = v > 0.f ? v : 0.f;
            partial[r] += v * w2;
        }
    }
#pragma unroll
    for (int r = 0; r < 4; ++r) {
#pragma unroll
        for (int o = 1; o < 16; o <<= 1) partial[r] += __shfl_xor(partial[r], o);
    }
    if (l15 == 0) {
#pragma unroll
        for (int r = 0; r < 4; ++r)
            s2p[(size_t)h * MROWS + row0 + l4 * 4 + r] = partial[r];
    }
}

__global__ __launch_bounds__(256) void k_red12(const float* __restrict__ s2p,
                                               float* __restrict__ s2)
{
    int t = blockIdx.x * 256 + threadIdx.x;
    if (t >= MROWS) return;
    float s = 0.f;
#pragma unroll
    for (int h = 0; h < HEADS; ++h) s += s2p[(size_t)h * MROWS + t];
    s2[t] = s;
}

// ---------------------------------------------------------------------------
// Layer-2 (heads=1, ch=1), no max-subtraction: one thread per (dst j, batch b).
// ---------------------------------------------------------------------------
__global__ void k_agg2(const float* __restrict__ s2,
                       const int* __restrict__ off,
                       const int* __restrict__ eid,
                       const int* __restrict__ src2,
                       const int* __restrict__ res2,
                       const float* __restrict__ asrc,
                       const float* __restrict__ adst,
                       const float* __restrict__ bias2,
                       float* __restrict__ out)
{
    int t = blockIdx.x * 256 + threadIdx.x;
    if (t >= 2 * ND2) return;
    int b = t / ND2, j = t - b * ND2;
    float a_s = asrc[0], a_d = adst[0];
    float edl = s2[(size_t)b * ND1 + res2[j]] * a_d;
    int beg = off[j], end = off[j + 1];
    float den = 0.f, num = 0.f;
    for (int p = beg; p < end; ++p) {
        int s = src2[eid[p]];
        float v = s2[b * ND1 + s];
        float w = __expf(lrelu(v * a_s + edl));
        den += w;
        num += w * v;
    }
    float o = (end > beg) ? num / (den + 1e-16f) : 0.f;
    out[(size_t)b * ND2 + j] = o + bias2[0];
}

// ---------------------------------------------------------------------------
extern "C" void kernel_launch(void* const* d_in, const int* in_sizes, int n_in,
                              void* d_out, int out_size, void* d_ws, size_t ws_size,
                              hipStream_t stream)
{
    const float* x        = (const float*)d_in[0];
    const int* n_id1      = (const int*)d_in[1];
    const int* res_n_id1  = (const int*)d_in[2];
    const int* src1       = (const int*)d_in[3];
    const int* dst1       = (const int*)d_in[4];
    const int* res_n_id2  = (const int*)d_in[5];
    const int* src2       = (const int*)d_in[6];
    const int* dst2       = (const int*)d_in[7];
    const float* W1       = (const float*)d_in[8];
    const float* att_src1 = (const float*)d_in[9];
    const float* att_dst1 = (const float*)d_in[10];
    const float* bias1    = (const float*)d_in[11];
    const float* W2       = (const float*)d_in[12];
    const float* att_src2 = (const float*)d_in[13];
    const float* att_dst2 = (const float*)d_in[14];
    const float* bias2    = (const float*)d_in[15];

    // workspace layout (16B aligned)
    unsigned short* xg   = (unsigned short*)d_ws;            // 4,096,000
    unsigned short* W1T  = xg + (size_t)2 * NS1 * F_IN;      //   196,608
    unsigned short* wswd = W1T + (size_t)K1 * F_IN;          //     4,096
    unsigned short* agg  = wswd + (size_t)32 * F_IN;         // 24,576,000
    float* es  = (float*)(agg + (size_t)2 * ND1 * K1);       //   384,000
    float* ed  = es + (size_t)2 * NS1 * HEADS;               //   384,000
    float* s2  = ed + (size_t)2 * NS1 * HEADS;               //    16,000
    int* deg   = (int*)(s2 + (size_t)2 * ND1);               // 12,000 (g1|g2)
    int* off1  = deg + (ND1 + ND2);                          // 8001
    int* off2  = off1 + (ND1 + 1);                           // 4001
    int* cur   = off2 + (ND2 + 1);                           // 12,000
    int* eid   = cur + (ND1 + ND2);                          // 160,000 (g1|g2)
    float* s2p = (float*)(eid + E1 + E2);                    // 192,000 f32

    // 1) fused prep (convA + convB + ws + deg zeroing)
    k_prep<<<4784 + 47, 256, 0, stream>>>(x, n_id1, W1, att_src1, att_dst1,
                                          xg, W1T, wswd, deg);

    // 2) scores (MFMA) + edge counting, fused
    k_escore_count<<<500 + (E1 + E2 + 255) / 256, 256, 0, stream>>>(
        xg, wswd, dst1, dst2, es, ed, deg);

    // 3) CSR scan + scatter
    k_scan2<<<2, 1024, 0, stream>>>(deg, off1, off2, cur);
    k_scatter2<<<(E1 + E2 + 255) / 256, 256, 0, stream>>>(dst1, dst2, cur, eid);

    // 4) layer-1 softmax-aggregate in F space
    k_agg1<<<dim3(ND1, B2), 256, 0, stream>>>(xg, es, ed, res_n_id1,
                                              off1, eid, src1, agg);

    // 5) projection + bias + relu + dot(W2) -> s2p (per head), then reduce
    k_out1<<<dim3(MROWS / 64, HEADS), 256, 0, stream>>>(agg, W1T, bias1, W2, s2p);
    k_red12<<<(MROWS + 255) / 256, 256, 0, stream>>>(s2p, s2);

    // 6) layer-2
    k_agg2<<<(2 * ND2 + 255) / 256, 256, 0, stream>>>(s2, off2, eid + E1, src2,
                                                      res_n_id2, att_src2,
                                                      att_dst2, bias2,
                                                      (float*)d_out);
}

// Round 7
// 123.900 us; speedup vs baseline: 1.6712x; 1.3265x over previous
//
#include <hip/hip_runtime.h>
#include <hip/hip_bf16.h>

// Sizes fixed by the problem
#define B2      2
#define NX      20000
#define F_IN    128
#define NS1     16000
#define ND1     8000
#define E1      100000
#define ND2     4000
#define E2      60000
#define HEADS   12
#define CH      128
#define K1      1536   // HEADS*CH
#define MROWS   (2*ND1) // 16000

typedef __bf16 bf16x8 __attribute__((ext_vector_type(8)));
typedef float  f32x4  __attribute__((ext_vector_type(4)));

static __device__ __forceinline__ float lrelu(float x) { return x > 0.f ? x : 0.2f * x; }

static __device__ __forceinline__ unsigned short f2bf(float f) {
    union { float f; unsigned u; } v; v.f = f;
    unsigned r = v.u + 0x7fffu + ((v.u >> 16) & 1u);
    return (unsigned short)(r >> 16);
}
static __device__ __forceinline__ float bf2f(unsigned short h) {
    union { unsigned u; float f; } v; v.u = ((unsigned)h) << 16;
    return v.f;
}

// async global->LDS, 16 bytes per lane; LDS dest is wave-uniform base + lane*16
static __device__ __forceinline__ void gld16(const void* g, void* l) {
    __builtin_amdgcn_global_load_lds(
        (const __attribute__((address_space(1))) unsigned int*)g,
        (__attribute__((address_space(3))) unsigned int*)l, 16, 0, 0);
}

// ---------------------------------------------------------------------------
// Fused prep: [0,4000) convA | [4000,4768) convB | [4768,4784) ws | rest: deg=0
// ---------------------------------------------------------------------------
__global__ __launch_bounds__(256) void k_prep(const float* __restrict__ x,
                                              const int* __restrict__ n_id,
                                              const float* __restrict__ W,
                                              const float* __restrict__ asrc,
                                              const float* __restrict__ adst,
                                              unsigned short* __restrict__ xg,
                                              unsigned short* __restrict__ WT,
                                              unsigned short* __restrict__ wswd,
                                              int* __restrict__ deg)
{
    const int bx = blockIdx.x;
    const int tid = threadIdx.x;
    if (bx < 4000) {
        int t = bx * 256 + tid;                      // float4 units
        int row = t >> 5;
        int c4 = (t & 31) << 2;
        int b = row >= NS1 ? 1 : 0;
        int node = n_id[row - b * NS1];
        const float4 v = *reinterpret_cast<const float4*>(
            x + ((size_t)(b * NX + node)) * F_IN + c4);
        ushort4 o;
        o.x = f2bf(v.x); o.y = f2bf(v.y); o.z = f2bf(v.z); o.w = f2bf(v.w);
        *reinterpret_cast<ushort4*>(xg + (size_t)row * F_IN + c4) = o;
    } else if (bx < 4768) {
        int t = (bx - 4000) * 256 + tid;             // 0..196607
        int k = t / K1;
        int n = t - k * K1;
        WT[(size_t)n * F_IN + k] = f2bf(W[t]);
    } else if (bx < 4784) {
        int t = (bx - 4768) * 256 + tid;             // 0..4095
        int n = t >> 7;
        int c = t & 127;
        float acc = 0.f;
        if (n < 24) {
            int h = n < 12 ? n : n - 12;
            const float* att = (n < 12 ? asrc : adst) + h * CH;
            const float* wr = W + (size_t)c * K1 + h * CH;
            for (int j = 0; j < CH; ++j) acc += wr[j] * att[j];
        }
        wswd[(size_t)n * F_IN + c] = f2bf(acc);
    } else {
        int t = (bx - 4784) * 256 + tid;
        if (t < ND1 + ND2) deg[t] = 0;
    }
}

// ---------------------------------------------------------------------------
// Fused: [0,500) scores MFMA | [500,1125) edge-count for both graphs.
// ---------------------------------------------------------------------------
__global__ __launch_bounds__(256) void k_escore_count(
        const unsigned short* __restrict__ xg,
        const unsigned short* __restrict__ wswd,
        const int* __restrict__ dst1, const int* __restrict__ dst2,
        float* __restrict__ es, float* __restrict__ ed,
        int* __restrict__ deg)
{
    const int tid = threadIdx.x;
    if (blockIdx.x < 500) {
        const int wave = tid >> 6, lane = tid & 63;
        const int l15 = lane & 15, l4 = lane >> 4;
        const int rt = blockIdx.x * 4 + wave;            // 0..1999
        const int row0 = rt * 16;
        const unsigned short* Ap = xg + (size_t)(row0 + l15) * F_IN + l4 * 8;

        f32x4 acc[2] = {f32x4{0,0,0,0}, f32x4{0,0,0,0}};
#pragma unroll
        for (int kk = 0; kk < 4; ++kk) {
            bf16x8 a = *reinterpret_cast<const bf16x8*>(Ap + kk * 32);
#pragma unroll
            for (int c = 0; c < 2; ++c) {
                bf16x8 b = *reinterpret_cast<const bf16x8*>(
                    wswd + (size_t)(c * 16 + l15) * F_IN + kk * 32 + l4 * 8);
                acc[c] = __builtin_amdgcn_mfma_f32_16x16x32_bf16(a, b, acc[c], 0, 0, 0);
            }
        }
#pragma unroll
        for (int c = 0; c < 2; ++c) {
            int col = c * 16 + l15;
#pragma unroll
            for (int r = 0; r < 4; ++r) {
                int row = row0 + l4 * 4 + r;
                float v = acc[c][r];
                if (col < 12)       es[(size_t)row * HEADS + col] = v;
                else if (col < 24)  ed[(size_t)row * HEADS + (col - 12)] = v;
            }
        }
    } else {
        int e = (blockIdx.x - 500) * 256 + tid;
        if (e < E1) atomicAdd(&deg[dst1[e]], 1);
        else if (e < E1 + E2) atomicAdd(&deg[ND1 + dst2[e - E1]], 1);
    }
}

// ---------------------------------------------------------------------------
// CSR scan (2 blocks: one per graph) -> scatter
// ---------------------------------------------------------------------------
static __device__ void scan_body(const int* __restrict__ deg, int n,
                                 int* __restrict__ off, int* __restrict__ cursor)
{
    __shared__ int wsum[16];
    __shared__ int carry_sh;
    int tid = threadIdx.x, lane = tid & 63, wid = tid >> 6;
    if (tid == 0) { carry_sh = 0; off[0] = 0; }
    __syncthreads();
    for (int base = 0; base < n; base += 1024) {
        int i = base + tid;
        int v = (i < n) ? deg[i] : 0;
        int s = v;
#pragma unroll
        for (int o = 1; o < 64; o <<= 1) {
            int t = __shfl_up(s, o);
            if (lane >= o) s += t;
        }
        if (lane == 63) wsum[wid] = s;
        __syncthreads();
        if (wid == 0) {
            int t = (lane < 16) ? wsum[lane] : 0;
#pragma unroll
            for (int o = 1; o < 16; o <<= 1) {
                int u = __shfl_up(t, o);
                if (lane >= o) t += u;
            }
            if (lane < 16) wsum[lane] = t;
        }
        __syncthreads();
        int carry = carry_sh;
        int wexcl = (wid == 0) ? 0 : wsum[wid - 1];
        int incl = carry + wexcl + s;
        if (i < n) { off[i + 1] = incl; cursor[i] = incl - v; }
        __syncthreads();
        if (tid == 0) carry_sh = carry + wsum[15];
        __syncthreads();
    }
}

__global__ __launch_bounds__(1024) void k_scan2(const int* __restrict__ deg,
                                                int* __restrict__ off1,
                                                int* __restrict__ off2,
                                                int* __restrict__ cur)
{
    if (blockIdx.x == 0) scan_body(deg, ND1, off1, cur);
    else                 scan_body(deg + ND1, ND2, off2, cur + ND1);
}

__global__ void k_scatter2(const int* __restrict__ dst1, const int* __restrict__ dst2,
                           int* __restrict__ cur, int* __restrict__ eid)
{
    int e = blockIdx.x * 256 + threadIdx.x;
    if (e < E1) {
        int p = atomicAdd(&cur[dst1[e]], 1);
        eid[p] = e;
    } else if (e < E1 + E2) {
        int p = atomicAdd(&cur[ND1 + dst2[e - E1]], 1);
        eid[E1 + p] = e - E1;
    }
}

// ---------------------------------------------------------------------------
// Layer-1 aggregate in F space, NO max-subtraction (shift-invariant softmax;
// scores are O(+-7) << 88, f32-exp safe). Block per (dst,b), 256 threads.
// ---------------------------------------------------------------------------
#define CHUNK 64
__global__ __launch_bounds__(256) void k_agg1(const unsigned short* __restrict__ xg,
                                              const float* __restrict__ es,
                                              const float* __restrict__ ed,
                                              const int* __restrict__ res1,
                                              const int* __restrict__ off,
                                              const int* __restrict__ eid,
                                              const int* __restrict__ src1,
                                              unsigned short* __restrict__ agg)
{
    const int i = blockIdx.x;   // dst node
    const int b = blockIdx.y;   // batch
    const int tid = threadIdx.x;
    const int c2 = (tid & 63) * 2;
    const int hg = tid >> 6;            // heads 3hg..3hg+2

    __shared__ float a_ch[CHUNK][HEADS];   // exp(lrelu(score)) per (edge, head)
    __shared__ int   src_sh[CHUNK];
    __shared__ float ed_sh[HEADS];

    const int beg = off[i], end = off[i + 1];
    const int deg = end - beg;

    if (tid < HEADS)
        ed_sh[tid] = ed[((size_t)(b * NS1 + res1[i])) * HEADS + tid];

    float acc[6] = {0.f, 0.f, 0.f, 0.f, 0.f, 0.f};
    float den[3] = {0.f, 0.f, 0.f};
    __syncthreads();

    for (int cbeg = 0; cbeg < deg; cbeg += CHUNK) {
        const int cnt = min(CHUNK, deg - cbeg);
        if (tid < cnt) src_sh[tid] = src1[eid[beg + cbeg + tid]];
        __syncthreads();
        for (int idx = tid; idx < cnt * HEADS; idx += 256) {
            int e = idx / HEADS, h = idx - e * HEADS;
            float al = es[((size_t)(b * NS1 + src_sh[e])) * HEADS + h] + ed_sh[h];
            a_ch[e][h] = __expf(lrelu(al));
        }
        __syncthreads();
#pragma unroll 2
        for (int e = 0; e < cnt; ++e) {
            int se = src_sh[e];
            unsigned xv = *reinterpret_cast<const unsigned*>(
                xg + ((size_t)(b * NS1 + se)) * F_IN + c2);
            float x0 = bf2f((unsigned short)(xv & 0xffff));
            float x1 = bf2f((unsigned short)(xv >> 16));
            float w0 = a_ch[e][3 * hg + 0];
            float w1 = a_ch[e][3 * hg + 1];
            float w2 = a_ch[e][3 * hg + 2];
            acc[0] += w0 * x0; acc[1] += w0 * x1;
            acc[2] += w1 * x0; acc[3] += w1 * x1;
            acc[4] += w2 * x0; acc[5] += w2 * x1;
            den[0] += w0; den[1] += w1; den[2] += w2;
        }
        __syncthreads();
    }

    const size_t rowbase = ((size_t)(b * ND1 + i)) * K1;
#pragma unroll
    for (int j = 0; j < 3; ++j) {
        float r = 1.f / (den[j] + 1e-16f);
        unsigned short o0 = f2bf(acc[2 * j] * r);
        unsigned short o1 = f2bf(acc[2 * j + 1] * r);
        unsigned pack = (unsigned)o0 | ((unsigned)o1 << 16);
        *reinterpret_cast<unsigned*>(agg + rowbase + (3 * hg + j) * CH + c2) = pack;
    }
}

// ---------------------------------------------------------------------------
// Post-aggregation projection v3: LDS-staged MFMA GEMM.
// Block (bx, h) = 128 rows x 1 head. A = agg[128x128] slice, B = W1_h^T
// (both 32 KB), staged via global_load_lds(16B) with pre-swizzled source
// (chunk ^= row&7) so swizzled ds_read_b128 is bank-minimal. 4 waves x
// (32 rows x 128 cols) = 64 MFMA/wave. Epilogue: bias+relu+dot(W2) ->
// s2p[h*MROWS+row]; k_red12 sums heads.
// ---------------------------------------------------------------------------
__global__ __launch_bounds__(256) void k_out1(const unsigned short* __restrict__ agg,
                                              const unsigned short* __restrict__ WT,
                                              const float* __restrict__ bias1,
                                              const float* __restrict__ W2,
                                              float* __restrict__ s2p)
{
    __shared__ unsigned short As[128 * 128];   // [row][k] chunk-swizzled
    __shared__ unsigned short Bs[128 * 128];   // [n][k]  chunk-swizzled

    const int tid = threadIdx.x;
    const int wv = tid >> 6, lane = tid & 63;
    const int l15 = lane & 15, l4 = lane >> 4;
    const int row0 = blockIdx.x * 128;
    const int h = blockIdx.y;

    // --- stage A and B: 8 passes each; wave covers 4 rows x 256B per pass ---
    {
        const unsigned short* ga = agg + (size_t)row0 * K1 + h * CH;
        const unsigned short* gb = WT + (size_t)(h * CH) * F_IN;
#pragma unroll
        for (int p = 0; p < 8; ++p) {
            int r = p * 16 + wv * 4 + l4;            // LDS row this lane feeds
            int cs = l15 ^ (r & 7);                  // pre-swizzled source chunk
            gld16(ga + (size_t)r * K1 + cs * 8, As + (p * 16 + wv * 4) * 128);
            gld16(gb + (size_t)r * F_IN + cs * 8, Bs + (p * 16 + wv * 4) * 128);
        }
    }
    __syncthreads();   // compiler drains vmcnt(0) before barrier

    // --- MFMA: wave computes rows [wv*32, wv*32+32) x all 128 cols ---
    f32x4 acc[2][8];
#pragma unroll
    for (int m = 0; m < 2; ++m)
#pragma unroll
        for (int c = 0; c < 8; ++c) acc[m][c] = f32x4{0, 0, 0, 0};

#pragma unroll
    for (int kk = 0; kk < 4; ++kk) {
        bf16x8 a[2];
#pragma unroll
        for (int m = 0; m < 2; ++m) {
            int r = wv * 32 + m * 16 + l15;
            int ch = (l4 + kk * 4) ^ (r & 7);
            a[m] = *reinterpret_cast<const bf16x8*>(As + r * 128 + ch * 8);
        }
#pragma unroll
        for (int c = 0; c < 8; ++c) {
            int n = c * 16 + l15;
            int ch = (l4 + kk * 4) ^ (n & 7);
            bf16x8 bb = *reinterpret_cast<const bf16x8*>(Bs + n * 128 + ch * 8);
#pragma unroll
            for (int m = 0; m < 2; ++m)
                acc[m][c] = __builtin_amdgcn_mfma_f32_16x16x32_bf16(a[m], bb,
                                                                    acc[m][c], 0, 0, 0);
        }
    }

    // --- epilogue: bias+relu+dot(W2), reduce over the 16 n-lanes ---
#pragma unroll
    for (int m = 0; m < 2; ++m) {
        float part[4] = {0.f, 0.f, 0.f, 0.f};
#pragma unroll
        for (int c = 0; c < 8; ++c) {
            int n = h * CH + c * 16 + l15;
            float bi = bias1[n];
            float w2 = W2[n];
#pragma unroll
            for (int r = 0; r < 4; ++r) {
                float v = acc[m][c][r] + bi;
                v = v > 0.f ? v : 0.f;
                part[r] += v * w2;
            }
        }
#pragma unroll
        for (int r = 0; r < 4; ++r) {
#pragma unroll
            for (int o = 1; o < 16; o <<= 1) part[r] += __shfl_xor(part[r], o);
        }
        if (l15 == 0) {
            int row = row0 + wv * 32 + m * 16 + l4 * 4;
#pragma unroll
            for (int r = 0; r < 4; ++r)
                s2p[(size_t)h * MROWS + row + r] = part[r];
        }
    }
}

__global__ __launch_bounds__(256) void k_red12(const float* __restrict__ s2p,
                                               float* __restrict__ s2)
{
    int t = blockIdx.x * 256 + threadIdx.x;
    if (t >= MROWS) return;
    float s = 0.f;
#pragma unroll
    for (int h = 0; h < HEADS; ++h) s += s2p[(size_t)h * MROWS + t];
    s2[t] = s;
}

// ---------------------------------------------------------------------------
// Layer-2 (heads=1, ch=1), no max-subtraction: one thread per (dst j, batch b).
// ---------------------------------------------------------------------------
__global__ void k_agg2(const float* __restrict__ s2,
                       const int* __restrict__ off,
                       const int* __restrict__ eid,
                       const int* __restrict__ src2,
                       const int* __restrict__ res2,
                       const float* __restrict__ asrc,
                       const float* __restrict__ adst,
                       const float* __restrict__ bias2,
                       float* __restrict__ out)
{
    int t = blockIdx.x * 256 + threadIdx.x;
    if (t >= 2 * ND2) return;
    int b = t / ND2, j = t - b * ND2;
    float a_s = asrc[0], a_d = adst[0];
    float edl = s2[(size_t)b * ND1 + res2[j]] * a_d;
    int beg = off[j], end = off[j + 1];
    float den = 0.f, num = 0.f;
    for (int p = beg; p < end; ++p) {
        int s = src2[eid[p]];
        float v = s2[b * ND1 + s];
        float w = __expf(lrelu(v * a_s + edl));
        den += w;
        num += w * v;
    }
    float o = (end > beg) ? num / (den + 1e-16f) : 0.f;
    out[(size_t)b * ND2 + j] = o + bias2[0];
}

// ---------------------------------------------------------------------------
extern "C" void kernel_launch(void* const* d_in, const int* in_sizes, int n_in,
                              void* d_out, int out_size, void* d_ws, size_t ws_size,
                              hipStream_t stream)
{
    const float* x        = (const float*)d_in[0];
    const int* n_id1      = (const int*)d_in[1];
    const int* res_n_id1  = (const int*)d_in[2];
    const int* src1       = (const int*)d_in[3];
    const int* dst1       = (const int*)d_in[4];
    const int* res_n_id2  = (const int*)d_in[5];
    const int* src2       = (const int*)d_in[6];
    const int* dst2       = (const int*)d_in[7];
    const float* W1       = (const float*)d_in[8];
    const float* att_src1 = (const float*)d_in[9];
    const float* att_dst1 = (const float*)d_in[10];
    const float* bias1    = (const float*)d_in[11];
    const float* W2       = (const float*)d_in[12];
    const float* att_src2 = (const float*)d_in[13];
    const float* att_dst2 = (const float*)d_in[14];
    const float* bias2    = (const float*)d_in[15];

    // workspace layout (16B aligned)
    unsigned short* xg   = (unsigned short*)d_ws;            // 4,096,000
    unsigned short* W1T  = xg + (size_t)2 * NS1 * F_IN;      //   196,608
    unsigned short* wswd = W1T + (size_t)K1 * F_IN;          //     4,096
    unsigned short* agg  = wswd + (size_t)32 * F_IN;         // 24,576,000
    float* es  = (float*)(agg + (size_t)2 * ND1 * K1);       //   384,000
    float* ed  = es + (size_t)2 * NS1 * HEADS;               //   384,000
    float* s2  = ed + (size_t)2 * NS1 * HEADS;               //    16,000
    int* deg   = (int*)(s2 + (size_t)2 * ND1);               // 12,000 (g1|g2)
    int* off1  = deg + (ND1 + ND2);                          // 8001
    int* off2  = off1 + (ND1 + 1);                           // 4001
    int* cur   = off2 + (ND2 + 1);                           // 12,000
    int* eid   = cur + (ND1 + ND2);                          // 160,000 (g1|g2)
    float* s2p = (float*)(eid + E1 + E2);                    // 192,000 f32

    // 1) fused prep (convA + convB + ws + deg zeroing)
    k_prep<<<4784 + 47, 256, 0, stream>>>(x, n_id1, W1, att_src1, att_dst1,
                                          xg, W1T, wswd, deg);

    // 2) scores (MFMA) + edge counting, fused
    k_escore_count<<<500 + (E1 + E2 + 255) / 256, 256, 0, stream>>>(
        xg, wswd, dst1, dst2, es, ed, deg);

    // 3) CSR scan + scatter
    k_scan2<<<2, 1024, 0, stream>>>(deg, off1, off2, cur);
    k_scatter2<<<(E1 + E2 + 255) / 256, 256, 0, stream>>>(dst1, dst2, cur, eid);

    // 4) layer-1 softmax-aggregate in F space
    k_agg1<<<dim3(ND1, B2), 256, 0, stream>>>(xg, es, ed, res_n_id1,
                                              off1, eid, src1, agg);

    // 5) projection + bias + relu + dot(W2) -> s2p (per head), then reduce
    k_out1<<<dim3(MROWS / 128, HEADS), 256, 0, stream>>>(agg, W1T, bias1, W2, s2p);
    k_red12<<<(MROWS + 255) / 256, 256, 0, stream>>>(s2p, s2);

    // 6) layer-2
    k_agg2<<<(2 * ND2 + 255) / 256, 256, 0, stream>>>(s2, off2, eid + E1, src2,
                                                      res_n_id2, att_src2,
                                                      att_dst2, bias2,
                                                      (float*)d_out);
}